// Round 16
// baseline (1135.434 us; speedup 1.0000x reference)
//
#include <hip/hip_runtime.h>

#define B_ 8
#define C_ 256
#define H_ 64
#define W_ 64
#define HW_ 4096
#define A_ 9
#define SITES 36864      // A_*HW_
#define NPOST 1000
#define XCLIPF 4.1351666f   // (float)4.135166556742356
#define IMGF 1024.0f

__device__ inline unsigned keyf(float v) {
  unsigned u = __float_as_uint(v);
  return (u & 0x80000000u) ? ~u : (u | 0x80000000u);  // ascending uint == ascending float
}

// ---------------- K1: 3x3 conv + bias + relu, bit-exact f32, 2 co x 4 px, HIGH OCCUPANCY ----
// The untested cell: pipelining shfl family (r7/r12/r14) at 4+ waves/SIMD.
// 72 acc + 18 window regs (~100 VGPR; weights in SGPRs) -> __launch_bounds__(256,4).
// Per iter: 72 FMA + 3 float4 loads + 6 shfl + 6 cndmask (~80% FMA fraction).
// Dispatch pair-fastest: adjacent blocks share one 18-row band of all channels (L2 local).
// Every (co,px,tap) fmaf chain over ci ascending + tap-ordered left-assoc epilogue are
// verbatim validated code; zrow stride-0 vertical halo = exact no-op. absmax 0.0 family.
// grid: B_*128*4 = 4096 blocks (b=blk&7 XCD swizzle); 256 threads = 16 rows x 16 chunks.
__global__ __launch_bounds__(256, 4) void conv3_2co4(
    const float* __restrict__ x, const float* __restrict__ w,
    const float* __restrict__ bias, const float* __restrict__ zrow,
    float* __restrict__ feats) {
#pragma clang fp contract(off)
  int b    = blockIdx.x & 7;           // XCD-affine (perf-only)
  int j    = blockIdx.x >> 3;          // 0..511
  int pair = j & 127;                  // fastest -> co-resident blocks share a band
  int band = j >> 7;                   // 0..3 (16-row band)
  int co0 = pair << 1, co1 = co0 + 1;
  int row16 = threadIdx.x >> 4;        // 0..15
  int chunk = threadIdx.x & 15;        // 0..15
  int gr = (band << 4) + row16;        // output row 0..63
  int c0 = chunk << 2;                 // col base (16B aligned)
  bool lef0 = (chunk == 0), rig0 = (chunk == 15);
  bool topz = (gr == 0), botz = (gr == 63);

  const float* xb = x + (size_t)b * C_ * HW_;
  const float* pT = topz ? zrow : (xb + (ptrdiff_t)(gr - 1) * W_ + c0);
  const float* pM = xb + (size_t)gr * W_ + c0;
  const float* pB = botz ? zrow : (xb + (size_t)(gr + 1) * W_ + c0);
  ptrdiff_t sT = topz ? 0 : HW_;
  ptrdiff_t sB = botz ? 0 : HW_;
  const float* wp0 = w + (size_t)co0 * (C_ * 9);
  const float* wp1 = w + (size_t)co1 * (C_ * 9);

  float acc0[4][9], acc1[4][9];        // [px][tap] for co0 / co1
#pragma unroll
  for (int p = 0; p < 4; ++p)
#pragma unroll
    for (int t = 0; t < 9; ++t) { acc0[p][t] = 0.f; acc1[p][t] = 0.f; }

  for (int ci = 0; ci < C_; ++ci) {
    float4 tA = ((const float4*)pT)[0];
    float4 mA = ((const float4*)pM)[0];
    float4 bA = ((const float4*)pB)[0];
    pT += sT; pM += HW_; pB += sB;

    float T[6], M[6], Bo[6];           // cols c0-1 .. c0+4
    T[1]=tA.x;  T[2]=tA.y;  T[3]=tA.z;  T[4]=tA.w;
    M[1]=mA.x;  M[2]=mA.y;  M[3]=mA.z;  M[4]=mA.w;
    Bo[1]=bA.x; Bo[2]=bA.y; Bo[3]=bA.z; Bo[4]=bA.w;

    T[0]  = __shfl_up(T[4], 1u);    if (lef0) T[0]  = 0.f;
    T[5]  = __shfl_down(T[1], 1u);  if (rig0) T[5]  = 0.f;
    M[0]  = __shfl_up(M[4], 1u);    if (lef0) M[0]  = 0.f;
    M[5]  = __shfl_down(M[1], 1u);  if (rig0) M[5]  = 0.f;
    Bo[0] = __shfl_up(Bo[4], 1u);   if (lef0) Bo[0] = 0.f;
    Bo[5] = __shfl_down(Bo[1], 1u); if (rig0) Bo[5] = 0.f;

    float w9a[9], w9b[9];
#pragma unroll
    for (int t = 0; t < 9; ++t) w9a[t] = wp0[ci * 9 + t];   // wave-uniform -> s_load
#pragma unroll
    for (int t = 0; t < 9; ++t) w9b[t] = wp1[ci * 9 + t];

#pragma unroll
    for (int p = 0; p < 4; ++p) {
      acc0[p][0] = fmaf(w9a[0], T[p],     acc0[p][0]);
      acc0[p][1] = fmaf(w9a[1], T[p+1],   acc0[p][1]);
      acc0[p][2] = fmaf(w9a[2], T[p+2],   acc0[p][2]);
      acc0[p][3] = fmaf(w9a[3], M[p],     acc0[p][3]);
      acc0[p][4] = fmaf(w9a[4], M[p+1],   acc0[p][4]);
      acc0[p][5] = fmaf(w9a[5], M[p+2],   acc0[p][5]);
      acc0[p][6] = fmaf(w9a[6], Bo[p],    acc0[p][6]);
      acc0[p][7] = fmaf(w9a[7], Bo[p+1],  acc0[p][7]);
      acc0[p][8] = fmaf(w9a[8], Bo[p+2],  acc0[p][8]);
      acc1[p][0] = fmaf(w9b[0], T[p],     acc1[p][0]);
      acc1[p][1] = fmaf(w9b[1], T[p+1],   acc1[p][1]);
      acc1[p][2] = fmaf(w9b[2], T[p+2],   acc1[p][2]);
      acc1[p][3] = fmaf(w9b[3], M[p],     acc1[p][3]);
      acc1[p][4] = fmaf(w9b[4], M[p+1],   acc1[p][4]);
      acc1[p][5] = fmaf(w9b[5], M[p+2],   acc1[p][5]);
      acc1[p][6] = fmaf(w9b[6], Bo[p],    acc1[p][6]);
      acc1[p][7] = fmaf(w9b[7], Bo[p+1],  acc1[p][7]);
      acc1[p][8] = fmaf(w9b[8], Bo[p+2],  acc1[p][8]);
    }
  }

  float bv0 = bias[co0], bv1 = bias[co1];
  float ov0[4], ov1[4];
#pragma unroll
  for (int p = 0; p < 4; ++p) {
    float a = 0.f;
#pragma unroll
    for (int t = 0; t < 9; ++t) a = a + acc0[p][t];  // tap-ordered, left-assoc
    a = a + bv0;
    ov0[p] = a > 0.f ? a : 0.f;
    float c = 0.f;
#pragma unroll
    for (int t = 0; t < 9; ++t) c = c + acc1[p][t];
    c = c + bv1;
    ov1[p] = c > 0.f ? c : 0.f;
  }
  float4* f0 = (float4*)(feats + ((size_t)b * C_ + co0) * HW_ + (size_t)gr * W_ + c0);
  float4* f1 = (float4*)(feats + ((size_t)b * C_ + co1) * HW_ + (size_t)gr * W_ + c0);
  f0[0] = make_float4(ov0[0], ov0[1], ov0[2], ov0[3]);
  f1[0] = make_float4(ov1[0], ov1[1], ov1[2], ov1[3]);
}

// ---------------- K2: 1x1 convs, 3-way channel split (15 chains/thread), bit-exact ----------------
__global__ __launch_bounds__(256) void conv1_split3(
    const float* __restrict__ feats,
    const float* __restrict__ box_w, const float* __restrict__ box_b,
    const float* __restrict__ obj_w, const float* __restrict__ obj_b,
    float* __restrict__ tbox, float* __restrict__ scores) {
#pragma clang fp contract(off)
  int gidx = blockIdx.x * 256 + threadIdx.x;   // [0, 3*B_*HW_)
  int cgrp = gidx >> 15;                        // 0..2
  int rem  = gidx & 32767;
  int b  = rem >> 12;
  int hw = rem & 4095;
  int cbase = cgrp * 15;
  const float* f = feats + (size_t)b * C_ * HW_ + hw;
  const float* wrow[15];
#pragma unroll
  for (int jj = 0; jj < 15; ++jj) {
    int c = cbase + jj;
    wrow[jj] = (c < 36) ? (box_w + (size_t)c * C_) : (obj_w + (size_t)(c - 36) * C_);
  }
  float acc[15];
#pragma unroll
  for (int jj = 0; jj < 15; ++jj) acc[jj] = 0.f;
  for (int ci = 0; ci < C_; ++ci) {
    float fv = f[(size_t)ci * HW_];
#pragma unroll
    for (int jj = 0; jj < 15; ++jj)
      acc[jj] = fmaf(wrow[jj][ci], fv, acc[jj]);
  }
#pragma unroll
  for (int jj = 0; jj < 15; ++jj) {
    int c = cbase + jj;
    if (c < 36) {
      int k = c / 9, a = c - k * 9;
      tbox[(size_t)b * 4 * SITES + (size_t)k * SITES + (size_t)a * HW_ + hw] = acc[jj] + box_b[c];
    } else {
      int a = c - 36;
      scores[(size_t)b * SITES + (size_t)a * HW_ + hw] = acc[jj] + obj_b[a];
    }
  }
}

// ---------------- K3: exact radix-select of the 1000th-smallest key per batch ----------------
__global__ __launch_bounds__(1024) void radix_select(
    const float* __restrict__ scores, unsigned* __restrict__ Kout,
    int* __restrict__ needEq, int* __restrict__ cnt, int* __restrict__ eqCnt) {
  int b = blockIdx.x;
  const float* s = scores + (size_t)b * SITES;
  __shared__ unsigned hist[256];
  __shared__ unsigned sh_prefix, sh_mask, sh_cless;
  __shared__ int sh_target;
  if (threadIdx.x == 0) { sh_prefix = 0; sh_mask = 0; sh_target = NPOST - 1; sh_cless = 0; }
  for (int shift = 24; shift >= 0; shift -= 8) {
    if (threadIdx.x < 256) hist[threadIdx.x] = 0;
    __syncthreads();
    unsigned prefix = sh_prefix, mask = sh_mask;
    for (int i = threadIdx.x; i < SITES; i += 1024) {
      unsigned k = keyf(s[i]);
      if ((k & mask) == prefix) atomicAdd(&hist[(k >> shift) & 255u], 1u);
    }
    __syncthreads();
    if (threadIdx.x == 0) {
      unsigned cum = 0; int t = sh_target; int v = 0;
      for (; v < 256; ++v) {
        unsigned h = hist[v];
        if (cum + h > (unsigned)t) break;
        cum += h;
      }
      sh_prefix |= ((unsigned)v) << shift;
      sh_mask   |= 0xFFu << shift;
      sh_target  = t - (int)cum;
      sh_cless  += cum;
    }
    __syncthreads();
  }
  if (threadIdx.x == 0) {
    Kout[b] = sh_prefix;
    needEq[b] = NPOST - (int)sh_cless;
    cnt[b] = 0;
    eqCnt[b] = 0;
  }
}

// ---------------- K4: compact k<K sites; collect k==K sites ----------------
__global__ __launch_bounds__(256) void compact_sel(
    const float* __restrict__ scores, const unsigned* __restrict__ Kout,
    int* __restrict__ cnt, int* __restrict__ sel,
    int* __restrict__ eqCnt, int* __restrict__ eqList) {
  int b = blockIdx.x / 144;
  int i = (blockIdx.x % 144) * 256 + threadIdx.x;
  unsigned K = Kout[b];
  unsigned k = keyf(scores[(size_t)b * SITES + i]);
  if (k < K) {
    int pos = atomicAdd(&cnt[b], 1);
    sel[b * 1024 + pos] = i;               // arbitrary order: order_decode re-sorts
  } else if (k == K) {
    int e = atomicAdd(&eqCnt[b], 1);
    if (e < 4096) eqList[b * 4096 + e] = i;
  }
}

// ---------------- K4b: take the needEq smallest-index equal-key sites ----------------
__global__ __launch_bounds__(256) void fix_eq(
    const int* __restrict__ cnt, const int* __restrict__ needEq,
    const int* __restrict__ eqCnt, const int* __restrict__ eqList,
    int* __restrict__ sel) {
  int b = blockIdx.x;
  int E = eqCnt[b]; if (E > 4096) E = 4096;
  int need = needEq[b];
  int base = cnt[b];
  const int* el = eqList + b * 4096;
  for (int t = threadIdx.x; t < E; t += 256) {
    int site = el[t];
    int rank = 0;
    for (int q = 0; q < E; ++q) rank += (el[q] < site);
    if (rank < need) sel[b * 1024 + base + rank] = site;
  }
}

// ---------------- K5: descending order + fused decode, 8 blocks/batch (125 ranks each) ----------------
__global__ __launch_bounds__(128) void order_decode(
    const float* __restrict__ scores, const int* __restrict__ sel,
    const float* __restrict__ tbox, float* __restrict__ s2, float* __restrict__ b2) {
#pragma clang fp contract(off)
  int b   = blockIdx.x >> 3;
  int r   = ((blockIdx.x & 7) * 125) + threadIdx.x;   // 125 ranks per block
  __shared__ float ss[NPOST];
  __shared__ int st[NPOST];
  for (int t = threadIdx.x; t < NPOST; t += 128) {
    int site = sel[b * 1024 + t];
    st[t] = site;
    ss[t] = scores[(size_t)b * SITES + site];
  }
  __syncthreads();
  if (threadIdx.x < 125) {
    float sr = ss[r]; int sir = st[r];
    int d = 0;
    for (int q = 0; q < NPOST; ++q) {
      float sq = ss[q];
      d += (int)((sq > sr) || (sq == sr && st[q] < sir));
    }
    s2[(size_t)b * NPOST + d] = sr;
    int site = sir;
    int a = site / HW_;
    int hw = site - a * HW_;
    int h = hw / W_, wc = hw - h * W_;
    int sidx = a / 3, ridx = a - sidx * 3;
    float scale = (sidx == 0) ? 128.f : ((sidx == 1) ? 256.f : 512.f);
    float ratio = (ridx == 0) ? 0.5f : ((ridx == 1) ? 1.0f : 2.0f);
    float sq = sqrtf(ratio);
    float wsa = scale / sq;
    float hsa = scale * sq;
    float cx = ((float)wc + 0.5f) * 16.f;
    float cy = ((float)h + 0.5f) * 16.f;
    float ax1 = cx - wsa * 0.5f;
    float ay1 = cy - hsa * 0.5f;
    float ax2 = cx + wsa * 0.5f;
    float ay2 = cy + hsa * 0.5f;
    float aw = ax2 - ax1, ah = ay2 - ay1;
    float m1 = 0.5f * aw, m2 = 0.5f * ah;
    float acx = ax1 + m1, acy = ay1 + m2;
    const float* tb = tbox + (size_t)b * 4 * SITES + site;
    float t0 = tb[0];
    float t1 = tb[SITES];
    float t2 = tb[2 * (size_t)SITES];
    float t3 = tb[3 * (size_t)SITES];
    if (t2 < -XCLIPF) t2 = -XCLIPF;
    if (t2 > XCLIPF) t2 = XCLIPF;
    if (t3 < -XCLIPF) t3 = -XCLIPF;
    if (t3 > XCLIPF) t3 = XCLIPF;
    float pm0 = t0 * aw;  float pcx = pm0 + acx;
    float pm1 = t1 * ah;  float pcy = pm1 + acy;
    float pw = expf(t2) * aw;
    float ph = expf(t3) * ah;
    float hw0 = 0.5f * pw, hh0 = 0.5f * ph;
    float x1 = pcx - hw0, y1 = pcy - hh0;
    float x2 = pcx + hw0, y2 = pcy + hh0;
    x1 = x1 < 0.f ? 0.f : (x1 > IMGF ? IMGF : x1);
    y1 = y1 < 0.f ? 0.f : (y1 > IMGF ? IMGF : y1);
    x2 = x2 < 0.f ? 0.f : (x2 > IMGF ? IMGF : x2);
    y2 = y2 < 0.f ? 0.f : (y2 > IMGF ? IMGF : y2);
    float* o = b2 + ((size_t)b * NPOST + d) * 4;
    o[0] = x1; o[1] = y1; o[2] = x2; o[3] = y2;
  }
}

// ---------------- K6a: suppression bitmask, f32 exact op order; conflict-fixed mapping ----------
__global__ __launch_bounds__(256) void mask_kernel(
    const float* __restrict__ b2, unsigned long long* __restrict__ sup) {
#pragma clang fp contract(off)
  int b = blockIdx.x / 63;
  int i0 = (blockIdx.x % 63) * 16;
  __shared__ float bs[NPOST * 4];
  __shared__ float area[NPOST];
  for (int t = threadIdx.x; t < NPOST * 4; t += 256) bs[t] = b2[(size_t)b * NPOST * 4 + t];
  __syncthreads();
  for (int t = threadIdx.x; t < NPOST; t += 256)
    area[t] = (bs[t * 4 + 2] - bs[t * 4]) * (bs[t * 4 + 3] - bs[t * 4 + 1]);
  __syncthreads();
  int i = i0 + (threadIdx.x & 15);
  int wd = threadIdx.x >> 4;
  if (i >= NPOST) return;
  float ax1 = bs[i * 4], ay1 = bs[i * 4 + 1], ax2 = bs[i * 4 + 2], ay2 = bs[i * 4 + 3];
  float aa = area[i];
  unsigned long long m = 0;
  for (int bit = 0; bit < 64; ++bit) {
    int j = wd * 64 + bit;
    if (j > i && j < NPOST) {
      float lx = fmaxf(ax1, bs[j * 4]);
      float ly = fmaxf(ay1, bs[j * 4 + 1]);
      float rx = fminf(ax2, bs[j * 4 + 2]);
      float ry = fminf(ay2, bs[j * 4 + 3]);
      float iw = rx - lx; if (iw < 0.f) iw = 0.f;
      float ih = ry - ly; if (ih < 0.f) ih = 0.f;
      float inter = iw * ih;
      float denom = (aa + area[j]) - inter;
      float iou = inter / denom;
      if (iou > 0.7f) m |= 1ull << bit;
    }
  }
  sup[((size_t)b * NPOST + i) * 16 + wd] = m;
}

// ---------------- K6b: wave-synchronous NMS scan, 8-deep prefetch + compaction ----------------
__global__ __launch_bounds__(64) void nms_out(
    const unsigned long long* __restrict__ sup, const float* __restrict__ b2,
    const float* __restrict__ s2, float* __restrict__ out) {
  int b = blockIdx.x;
  int lane = threadIdx.x;
  unsigned long long kw = 0;
  if (lane < 16) kw = (lane < 15) ? ~0ull : ((1ull << 40) - 1);  // bits 960..999 valid
  const unsigned long long* ms = sup + (size_t)b * NPOST * 16;
  unsigned long long mb[8];
#pragma unroll
  for (int k = 0; k < 8; ++k)
    mb[k] = (lane < 16) ? ms[(size_t)k * 16 + lane] : 0ull;
  for (int i0 = 0; i0 < NPOST; i0 += 8) {          // 1000 = 8*125
    unsigned long long nb[8];
#pragma unroll
    for (int k = 0; k < 8; ++k) {
      int nx = i0 + 8 + k;
      nb[k] = (nx < NPOST && lane < 16) ? ms[(size_t)nx * 16 + lane] : 0ull;
    }
#pragma unroll
    for (int k = 0; k < 8; ++k) {
      int i = i0 + k;
      unsigned long long w = __shfl(kw, i >> 6, 64);  // broadcast word holding bit i
      if ((w >> (i & 63)) & 1ull) {                   // wave-uniform branch
        if (lane < 16) kw &= ~mb[k];                  // bit i never set in row i (j>i only)
      }
    }
#pragma unroll
    for (int k = 0; k < 8; ++k) mb[k] = nb[k];
  }
  __shared__ unsigned long long keeps[16];
  if (lane < 16) keeps[lane] = kw;
  __syncthreads();
  int total = 0;
#pragma unroll
  for (int k = 0; k < 16; ++k) total += __popcll(keeps[k]);
  for (int i = lane; i < NPOST; i += 64) {
    int w = i >> 6;
    int before = 0;
    for (int k = 0; k < w; ++k) before += __popcll(keeps[k]);
    before += __popcll(keeps[w] & ((1ull << (i & 63)) - 1));
    bool kept = (keeps[w] >> (i & 63)) & 1ull;
    if (kept) {
      size_t ob = (size_t)b * (NPOST * 5) + (size_t)before * 5;
      const float* src = b2 + ((size_t)b * NPOST + i) * 4;
      out[ob + 0] = src[0];
      out[ob + 1] = src[1];
      out[ob + 2] = src[2];
      out[ob + 3] = src[3];
      out[ob + 4] = s2[(size_t)b * NPOST + i];
    }
    if (i >= total) {
      size_t ob = (size_t)b * (NPOST * 5) + (size_t)i * 5;
      for (int c = 0; c < 5; ++c) out[ob + c] = 0.f;
    }
  }
}

extern "C" void kernel_launch(void* const* d_in, const int* in_sizes, int n_in,
                              void* d_out, int out_size, void* d_ws, size_t ws_size,
                              hipStream_t stream) {
  const float *x = nullptr, *conv_w = nullptr, *conv_b = nullptr,
              *box_w = nullptr, *box_b = nullptr, *obj_w = nullptr, *obj_b = nullptr;
  for (int i = 0; i < n_in; ++i) {
    switch (in_sizes[i]) {
      case 8388608: x = (const float*)d_in[i]; break;
      case 589824:  conv_w = (const float*)d_in[i]; break;
      case 256:     conv_b = (const float*)d_in[i]; break;
      case 9216:    box_w = (const float*)d_in[i]; break;
      case 36:      box_b = (const float*)d_in[i]; break;
      case 2304:    obj_w = (const float*)d_in[i]; break;
      case 9:       obj_b = (const float*)d_in[i]; break;
    }
  }
  float* out = (float*)d_out;

  char* p = (char*)d_ws;
  auto alloc = [&](size_t n) { char* q = p; p += (n + 255) & ~255ull; return (void*)q; };
  float* feats  = (float*)alloc((size_t)B_ * C_ * HW_ * 4);       // 33.55 MB
  float* tbox   = (float*)alloc((size_t)B_ * 4 * SITES * 4);      // 4.72 MB
  float* scores = (float*)alloc((size_t)B_ * SITES * 4);          // 1.18 MB
  float* zrow   = (float*)alloc(256);                              // zero halo row
  unsigned* Kout = (unsigned*)alloc(B_ * 4);
  int* needEq    = (int*)alloc(B_ * 4);
  int* cnt       = (int*)alloc(B_ * 4);
  int* eqCnt     = (int*)alloc(B_ * 4);
  int* eqList    = (int*)alloc((size_t)B_ * 4096 * 4);
  int* sel       = (int*)alloc((size_t)B_ * 1024 * 4);
  float* s2      = (float*)alloc((size_t)B_ * NPOST * 4);
  float* b2      = (float*)alloc((size_t)B_ * NPOST * 4 * 4);
  unsigned long long* sup = (unsigned long long*)alloc((size_t)B_ * NPOST * 16 * 8); // 1.02 MB

  hipMemsetAsync(zrow, 0, 256, stream);
  hipLaunchKernelGGL(conv3_2co4, dim3(B_ * 128 * 4), dim3(256), 0, stream,
                     x, conv_w, conv_b, zrow, feats);
  hipLaunchKernelGGL(conv1_split3, dim3(3 * B_ * HW_ / 256), dim3(256), 0, stream,
                     feats, box_w, box_b, obj_w, obj_b, tbox, scores);
  hipLaunchKernelGGL(radix_select, dim3(B_), dim3(1024), 0, stream,
                     scores, Kout, needEq, cnt, eqCnt);
  hipLaunchKernelGGL(compact_sel, dim3(B_ * 144), dim3(256), 0, stream,
                     scores, Kout, cnt, sel, eqCnt, eqList);
  hipLaunchKernelGGL(fix_eq, dim3(B_), dim3(256), 0, stream,
                     cnt, needEq, eqCnt, eqList, sel);
  hipLaunchKernelGGL(order_decode, dim3(B_ * 8), dim3(128), 0, stream,
                     scores, sel, tbox, s2, b2);
  hipLaunchKernelGGL(mask_kernel, dim3(B_ * 63), dim3(256), 0, stream, b2, sup);
  hipLaunchKernelGGL(nms_out, dim3(B_), dim3(64), 0, stream, sup, b2, s2, out);
}

// Round 17
// 1101.217 us; speedup vs baseline: 1.0311x; 1.0311x over previous
//
#include <hip/hip_runtime.h>

#define B_ 8
#define C_ 256
#define H_ 64
#define W_ 64
#define HW_ 4096
#define A_ 9
#define SITES 36864      // A_*HW_
#define NPOST 1000
#define XCLIPF 4.1351666f   // (float)4.135166556742356
#define IMGF 1024.0f

__device__ inline unsigned keyf(float v) {
  unsigned u = __float_as_uint(v);
  return (u & 0x80000000u) ? ~u : (u | 0x80000000u);  // ascending uint == ascending float
}

// ---------------- K1: 3x3 conv + bias + relu, bit-exact f32, 2 co x 4 px, 4 waves/SIMD ----
// VERBATIM round-16 kernel (best measured conv family: ~705us, VALUBusy 77%, absmax 0.0).
__global__ __launch_bounds__(256, 4) void conv3_2co4(
    const float* __restrict__ x, const float* __restrict__ w,
    const float* __restrict__ bias, const float* __restrict__ zrow,
    float* __restrict__ feats) {
#pragma clang fp contract(off)
  int b    = blockIdx.x & 7;           // XCD-affine (perf-only)
  int j    = blockIdx.x >> 3;          // 0..511
  int pair = j & 127;                  // fastest -> co-resident blocks share a band
  int band = j >> 7;                   // 0..3 (16-row band)
  int co0 = pair << 1, co1 = co0 + 1;
  int row16 = threadIdx.x >> 4;        // 0..15
  int chunk = threadIdx.x & 15;        // 0..15
  int gr = (band << 4) + row16;        // output row 0..63
  int c0 = chunk << 2;                 // col base (16B aligned)
  bool lef0 = (chunk == 0), rig0 = (chunk == 15);
  bool topz = (gr == 0), botz = (gr == 63);

  const float* xb = x + (size_t)b * C_ * HW_;
  const float* pT = topz ? zrow : (xb + (ptrdiff_t)(gr - 1) * W_ + c0);
  const float* pM = xb + (size_t)gr * W_ + c0;
  const float* pB = botz ? zrow : (xb + (size_t)(gr + 1) * W_ + c0);
  ptrdiff_t sT = topz ? 0 : HW_;
  ptrdiff_t sB = botz ? 0 : HW_;
  const float* wp0 = w + (size_t)co0 * (C_ * 9);
  const float* wp1 = w + (size_t)co1 * (C_ * 9);

  float acc0[4][9], acc1[4][9];        // [px][tap] for co0 / co1
#pragma unroll
  for (int p = 0; p < 4; ++p)
#pragma unroll
    for (int t = 0; t < 9; ++t) { acc0[p][t] = 0.f; acc1[p][t] = 0.f; }

  for (int ci = 0; ci < C_; ++ci) {
    float4 tA = ((const float4*)pT)[0];
    float4 mA = ((const float4*)pM)[0];
    float4 bA = ((const float4*)pB)[0];
    pT += sT; pM += HW_; pB += sB;

    float T[6], M[6], Bo[6];           // cols c0-1 .. c0+4
    T[1]=tA.x;  T[2]=tA.y;  T[3]=tA.z;  T[4]=tA.w;
    M[1]=mA.x;  M[2]=mA.y;  M[3]=mA.z;  M[4]=mA.w;
    Bo[1]=bA.x; Bo[2]=bA.y; Bo[3]=bA.z; Bo[4]=bA.w;

    T[0]  = __shfl_up(T[4], 1u);    if (lef0) T[0]  = 0.f;
    T[5]  = __shfl_down(T[1], 1u);  if (rig0) T[5]  = 0.f;
    M[0]  = __shfl_up(M[4], 1u);    if (lef0) M[0]  = 0.f;
    M[5]  = __shfl_down(M[1], 1u);  if (rig0) M[5]  = 0.f;
    Bo[0] = __shfl_up(Bo[4], 1u);   if (lef0) Bo[0] = 0.f;
    Bo[5] = __shfl_down(Bo[1], 1u); if (rig0) Bo[5] = 0.f;

    float w9a[9], w9b[9];
#pragma unroll
    for (int t = 0; t < 9; ++t) w9a[t] = wp0[ci * 9 + t];   // wave-uniform -> s_load
#pragma unroll
    for (int t = 0; t < 9; ++t) w9b[t] = wp1[ci * 9 + t];

#pragma unroll
    for (int p = 0; p < 4; ++p) {
      acc0[p][0] = fmaf(w9a[0], T[p],     acc0[p][0]);
      acc0[p][1] = fmaf(w9a[1], T[p+1],   acc0[p][1]);
      acc0[p][2] = fmaf(w9a[2], T[p+2],   acc0[p][2]);
      acc0[p][3] = fmaf(w9a[3], M[p],     acc0[p][3]);
      acc0[p][4] = fmaf(w9a[4], M[p+1],   acc0[p][4]);
      acc0[p][5] = fmaf(w9a[5], M[p+2],   acc0[p][5]);
      acc0[p][6] = fmaf(w9a[6], Bo[p],    acc0[p][6]);
      acc0[p][7] = fmaf(w9a[7], Bo[p+1],  acc0[p][7]);
      acc0[p][8] = fmaf(w9a[8], Bo[p+2],  acc0[p][8]);
      acc1[p][0] = fmaf(w9b[0], T[p],     acc1[p][0]);
      acc1[p][1] = fmaf(w9b[1], T[p+1],   acc1[p][1]);
      acc1[p][2] = fmaf(w9b[2], T[p+2],   acc1[p][2]);
      acc1[p][3] = fmaf(w9b[3], M[p],     acc1[p][3]);
      acc1[p][4] = fmaf(w9b[4], M[p+1],   acc1[p][4]);
      acc1[p][5] = fmaf(w9b[5], M[p+2],   acc1[p][5]);
      acc1[p][6] = fmaf(w9b[6], Bo[p],    acc1[p][6]);
      acc1[p][7] = fmaf(w9b[7], Bo[p+1],  acc1[p][7]);
      acc1[p][8] = fmaf(w9b[8], Bo[p+2],  acc1[p][8]);
    }
  }

  float bv0 = bias[co0], bv1 = bias[co1];
  float ov0[4], ov1[4];
#pragma unroll
  for (int p = 0; p < 4; ++p) {
    float a = 0.f;
#pragma unroll
    for (int t = 0; t < 9; ++t) a = a + acc0[p][t];  // tap-ordered, left-assoc
    a = a + bv0;
    ov0[p] = a > 0.f ? a : 0.f;
    float c = 0.f;
#pragma unroll
    for (int t = 0; t < 9; ++t) c = c + acc1[p][t];
    c = c + bv1;
    ov1[p] = c > 0.f ? c : 0.f;
  }
  float4* f0 = (float4*)(feats + ((size_t)b * C_ + co0) * HW_ + (size_t)gr * W_ + c0);
  float4* f1 = (float4*)(feats + ((size_t)b * C_ + co1) * HW_ + (size_t)gr * W_ + c0);
  f0[0] = make_float4(ov0[0], ov0[1], ov0[2], ov0[3]);
  f1[0] = make_float4(ov1[0], ov1[1], ov1[2], ov1[3]);
}

// ---------------- K2: 1x1 convs, 3-way channel split (15 chains/thread), bit-exact ----------------
__global__ __launch_bounds__(256) void conv1_split3(
    const float* __restrict__ feats,
    const float* __restrict__ box_w, const float* __restrict__ box_b,
    const float* __restrict__ obj_w, const float* __restrict__ obj_b,
    float* __restrict__ tbox, float* __restrict__ scores) {
#pragma clang fp contract(off)
  int gidx = blockIdx.x * 256 + threadIdx.x;   // [0, 3*B_*HW_)
  int cgrp = gidx >> 15;                        // 0..2
  int rem  = gidx & 32767;
  int b  = rem >> 12;
  int hw = rem & 4095;
  int cbase = cgrp * 15;
  const float* f = feats + (size_t)b * C_ * HW_ + hw;
  const float* wrow[15];
#pragma unroll
  for (int jj = 0; jj < 15; ++jj) {
    int c = cbase + jj;
    wrow[jj] = (c < 36) ? (box_w + (size_t)c * C_) : (obj_w + (size_t)(c - 36) * C_);
  }
  float acc[15];
#pragma unroll
  for (int jj = 0; jj < 15; ++jj) acc[jj] = 0.f;
  for (int ci = 0; ci < C_; ++ci) {
    float fv = f[(size_t)ci * HW_];
#pragma unroll
    for (int jj = 0; jj < 15; ++jj)
      acc[jj] = fmaf(wrow[jj][ci], fv, acc[jj]);
  }
#pragma unroll
  for (int jj = 0; jj < 15; ++jj) {
    int c = cbase + jj;
    if (c < 36) {
      int k = c / 9, a = c - k * 9;
      tbox[(size_t)b * 4 * SITES + (size_t)k * SITES + (size_t)a * HW_ + hw] = acc[jj] + box_b[c];
    } else {
      int a = c - 36;
      scores[(size_t)b * SITES + (size_t)a * HW_ + hw] = acc[jj] + obj_b[a];
    }
  }
}

// ---------------- K3: FUSED radix-select + compact + fix_eq + order + decode ----------------
// One block per batch, 1024 threads; all intermediate state in LDS; replaces 4 launches.
// Phase math is verbatim the validated kernels: selection SET identical (order within
// sel[] irrelevant — phase D re-sorts by (score desc, site asc)); decode op-for-op.
__global__ __launch_bounds__(1024) void select_order_decode(
    const float* __restrict__ scores, const float* __restrict__ tbox,
    float* __restrict__ s2, float* __restrict__ b2) {
#pragma clang fp contract(off)
  int b = blockIdx.x;
  const float* s = scores + (size_t)b * SITES;
  __shared__ unsigned hist[256];
  __shared__ unsigned sh_prefix, sh_mask, sh_cless;
  __shared__ int sh_target;
  __shared__ int cnt, eqCnt;
  __shared__ int sel[NPOST];
  __shared__ int eqList[1024];
  __shared__ float ss[NPOST];
  __shared__ int st[NPOST];

  // ---- Phase A: radix select (verbatim logic) ----
  if (threadIdx.x == 0) {
    sh_prefix = 0; sh_mask = 0; sh_target = NPOST - 1; sh_cless = 0;
    cnt = 0; eqCnt = 0;
  }
  for (int shift = 24; shift >= 0; shift -= 8) {
    if (threadIdx.x < 256) hist[threadIdx.x] = 0;
    __syncthreads();
    unsigned prefix = sh_prefix, mask = sh_mask;
    for (int i = threadIdx.x; i < SITES; i += 1024) {
      unsigned k = keyf(s[i]);
      if ((k & mask) == prefix) atomicAdd(&hist[(k >> shift) & 255u], 1u);
    }
    __syncthreads();
    if (threadIdx.x == 0) {
      unsigned cum = 0; int t = sh_target; int v = 0;
      for (; v < 256; ++v) {
        unsigned h = hist[v];
        if (cum + h > (unsigned)t) break;
        cum += h;
      }
      sh_prefix |= ((unsigned)v) << shift;
      sh_mask   |= 0xFFu << shift;
      sh_target  = t - (int)cum;
      sh_cless  += cum;
    }
    __syncthreads();
  }
  unsigned K = sh_prefix;
  int need = NPOST - (int)sh_cless;

  // ---- Phase B: compact k<K into sel, k==K into eqList ----
  for (int i = threadIdx.x; i < SITES; i += 1024) {
    unsigned k = keyf(s[i]);
    if (k < K) {
      int pos = atomicAdd(&cnt, 1);
      sel[pos] = i;
    } else if (k == K) {
      int e = atomicAdd(&eqCnt, 1);
      if (e < 1024) eqList[e] = i;
    }
  }
  __syncthreads();

  // ---- Phase C: append the `need` smallest-index equal-key sites ----
  int E = eqCnt; if (E > 1024) E = 1024;
  int base = cnt;   // == count_less
  for (int t = threadIdx.x; t < E; t += 1024) {
    int site = eqList[t];
    int rank = 0;
    for (int q = 0; q < E; ++q) rank += (eqList[q] < site);
    if (rank < need) sel[base + rank] = site;
  }
  __syncthreads();

  // ---- Phase D: load (score,site), exact descending order + fused decode (verbatim) ----
  for (int t = threadIdx.x; t < NPOST; t += 1024) {
    int site = sel[t];
    st[t] = site;
    ss[t] = s[site];
  }
  __syncthreads();
  if (threadIdx.x < NPOST) {
    int r = threadIdx.x;
    float sr = ss[r]; int sir = st[r];
    int d = 0;
    for (int q = 0; q < NPOST; ++q) {
      float sq = ss[q];
      d += (int)((sq > sr) || (sq == sr && st[q] < sir));
    }
    s2[(size_t)b * NPOST + d] = sr;
    int site = sir;
    int a = site / HW_;
    int hw = site - a * HW_;
    int h = hw / W_, wc = hw - h * W_;
    int sidx = a / 3, ridx = a - sidx * 3;
    float scale = (sidx == 0) ? 128.f : ((sidx == 1) ? 256.f : 512.f);
    float ratio = (ridx == 0) ? 0.5f : ((ridx == 1) ? 1.0f : 2.0f);
    float sq = sqrtf(ratio);
    float wsa = scale / sq;
    float hsa = scale * sq;
    float cx = ((float)wc + 0.5f) * 16.f;
    float cy = ((float)h + 0.5f) * 16.f;
    float ax1 = cx - wsa * 0.5f;
    float ay1 = cy - hsa * 0.5f;
    float ax2 = cx + wsa * 0.5f;
    float ay2 = cy + hsa * 0.5f;
    float aw = ax2 - ax1, ah = ay2 - ay1;
    float m1 = 0.5f * aw, m2 = 0.5f * ah;
    float acx = ax1 + m1, acy = ay1 + m2;
    const float* tb = tbox + (size_t)b * 4 * SITES + site;
    float t0 = tb[0];
    float t1 = tb[SITES];
    float t2 = tb[2 * (size_t)SITES];
    float t3 = tb[3 * (size_t)SITES];
    if (t2 < -XCLIPF) t2 = -XCLIPF;
    if (t2 > XCLIPF) t2 = XCLIPF;
    if (t3 < -XCLIPF) t3 = -XCLIPF;
    if (t3 > XCLIPF) t3 = XCLIPF;
    float pm0 = t0 * aw;  float pcx = pm0 + acx;
    float pm1 = t1 * ah;  float pcy = pm1 + acy;
    float pw = expf(t2) * aw;
    float ph = expf(t3) * ah;
    float hw0 = 0.5f * pw, hh0 = 0.5f * ph;
    float x1 = pcx - hw0, y1 = pcy - hh0;
    float x2 = pcx + hw0, y2 = pcy + hh0;
    x1 = x1 < 0.f ? 0.f : (x1 > IMGF ? IMGF : x1);
    y1 = y1 < 0.f ? 0.f : (y1 > IMGF ? IMGF : y1);
    x2 = x2 < 0.f ? 0.f : (x2 > IMGF ? IMGF : x2);
    y2 = y2 < 0.f ? 0.f : (y2 > IMGF ? IMGF : y2);
    float* o = b2 + ((size_t)b * NPOST + d) * 4;
    o[0] = x1; o[1] = y1; o[2] = x2; o[3] = y2;
  }
}

// ---------------- K4a: suppression bitmask, f32 exact op order; conflict-fixed mapping ----------
__global__ __launch_bounds__(256) void mask_kernel(
    const float* __restrict__ b2, unsigned long long* __restrict__ sup) {
#pragma clang fp contract(off)
  int b = blockIdx.x / 63;
  int i0 = (blockIdx.x % 63) * 16;
  __shared__ float bs[NPOST * 4];
  __shared__ float area[NPOST];
  for (int t = threadIdx.x; t < NPOST * 4; t += 256) bs[t] = b2[(size_t)b * NPOST * 4 + t];
  __syncthreads();
  for (int t = threadIdx.x; t < NPOST; t += 256)
    area[t] = (bs[t * 4 + 2] - bs[t * 4]) * (bs[t * 4 + 3] - bs[t * 4 + 1]);
  __syncthreads();
  int i = i0 + (threadIdx.x & 15);
  int wd = threadIdx.x >> 4;
  if (i >= NPOST) return;
  float ax1 = bs[i * 4], ay1 = bs[i * 4 + 1], ax2 = bs[i * 4 + 2], ay2 = bs[i * 4 + 3];
  float aa = area[i];
  unsigned long long m = 0;
  for (int bit = 0; bit < 64; ++bit) {
    int j = wd * 64 + bit;
    if (j > i && j < NPOST) {
      float lx = fmaxf(ax1, bs[j * 4]);
      float ly = fmaxf(ay1, bs[j * 4 + 1]);
      float rx = fminf(ax2, bs[j * 4 + 2]);
      float ry = fminf(ay2, bs[j * 4 + 3]);
      float iw = rx - lx; if (iw < 0.f) iw = 0.f;
      float ih = ry - ly; if (ih < 0.f) ih = 0.f;
      float inter = iw * ih;
      float denom = (aa + area[j]) - inter;
      float iou = inter / denom;
      if (iou > 0.7f) m |= 1ull << bit;
    }
  }
  sup[((size_t)b * NPOST + i) * 16 + wd] = m;
}

// ---------------- K4b: wave-synchronous NMS scan, 8-deep prefetch + compaction ----------------
__global__ __launch_bounds__(64) void nms_out(
    const unsigned long long* __restrict__ sup, const float* __restrict__ b2,
    const float* __restrict__ s2, float* __restrict__ out) {
  int b = blockIdx.x;
  int lane = threadIdx.x;
  unsigned long long kw = 0;
  if (lane < 16) kw = (lane < 15) ? ~0ull : ((1ull << 40) - 1);  // bits 960..999 valid
  const unsigned long long* ms = sup + (size_t)b * NPOST * 16;
  unsigned long long mb[8];
#pragma unroll
  for (int k = 0; k < 8; ++k)
    mb[k] = (lane < 16) ? ms[(size_t)k * 16 + lane] : 0ull;
  for (int i0 = 0; i0 < NPOST; i0 += 8) {          // 1000 = 8*125
    unsigned long long nb[8];
#pragma unroll
    for (int k = 0; k < 8; ++k) {
      int nx = i0 + 8 + k;
      nb[k] = (nx < NPOST && lane < 16) ? ms[(size_t)nx * 16 + lane] : 0ull;
    }
#pragma unroll
    for (int k = 0; k < 8; ++k) {
      int i = i0 + k;
      unsigned long long w = __shfl(kw, i >> 6, 64);  // broadcast word holding bit i
      if ((w >> (i & 63)) & 1ull) {                   // wave-uniform branch
        if (lane < 16) kw &= ~mb[k];                  // bit i never set in row i (j>i only)
      }
    }
#pragma unroll
    for (int k = 0; k < 8; ++k) mb[k] = nb[k];
  }
  __shared__ unsigned long long keeps[16];
  if (lane < 16) keeps[lane] = kw;
  __syncthreads();
  int total = 0;
#pragma unroll
  for (int k = 0; k < 16; ++k) total += __popcll(keeps[k]);
  for (int i = lane; i < NPOST; i += 64) {
    int w = i >> 6;
    int before = 0;
    for (int k = 0; k < w; ++k) before += __popcll(keeps[k]);
    before += __popcll(keeps[w] & ((1ull << (i & 63)) - 1));
    bool kept = (keeps[w] >> (i & 63)) & 1ull;
    if (kept) {
      size_t ob = (size_t)b * (NPOST * 5) + (size_t)before * 5;
      const float* src = b2 + ((size_t)b * NPOST + i) * 4;
      out[ob + 0] = src[0];
      out[ob + 1] = src[1];
      out[ob + 2] = src[2];
      out[ob + 3] = src[3];
      out[ob + 4] = s2[(size_t)b * NPOST + i];
    }
    if (i >= total) {
      size_t ob = (size_t)b * (NPOST * 5) + (size_t)i * 5;
      for (int c = 0; c < 5; ++c) out[ob + c] = 0.f;
    }
  }
}

extern "C" void kernel_launch(void* const* d_in, const int* in_sizes, int n_in,
                              void* d_out, int out_size, void* d_ws, size_t ws_size,
                              hipStream_t stream) {
  const float *x = nullptr, *conv_w = nullptr, *conv_b = nullptr,
              *box_w = nullptr, *box_b = nullptr, *obj_w = nullptr, *obj_b = nullptr;
  for (int i = 0; i < n_in; ++i) {
    switch (in_sizes[i]) {
      case 8388608: x = (const float*)d_in[i]; break;
      case 589824:  conv_w = (const float*)d_in[i]; break;
      case 256:     conv_b = (const float*)d_in[i]; break;
      case 9216:    box_w = (const float*)d_in[i]; break;
      case 36:      box_b = (const float*)d_in[i]; break;
      case 2304:    obj_w = (const float*)d_in[i]; break;
      case 9:       obj_b = (const float*)d_in[i]; break;
    }
  }
  float* out = (float*)d_out;

  char* p = (char*)d_ws;
  auto alloc = [&](size_t n) { char* q = p; p += (n + 255) & ~255ull; return (void*)q; };
  float* feats  = (float*)alloc((size_t)B_ * C_ * HW_ * 4);       // 33.55 MB
  float* tbox   = (float*)alloc((size_t)B_ * 4 * SITES * 4);      // 4.72 MB
  float* scores = (float*)alloc((size_t)B_ * SITES * 4);          // 1.18 MB
  float* zrow   = (float*)alloc(256);                              // zero halo row
  float* s2     = (float*)alloc((size_t)B_ * NPOST * 4);
  float* b2     = (float*)alloc((size_t)B_ * NPOST * 4 * 4);
  unsigned long long* sup = (unsigned long long*)alloc((size_t)B_ * NPOST * 16 * 8); // 1.02 MB

  hipMemsetAsync(zrow, 0, 256, stream);
  hipLaunchKernelGGL(conv3_2co4, dim3(B_ * 128 * 4), dim3(256), 0, stream,
                     x, conv_w, conv_b, zrow, feats);
  hipLaunchKernelGGL(conv1_split3, dim3(3 * B_ * HW_ / 256), dim3(256), 0, stream,
                     feats, box_w, box_b, obj_w, obj_b, tbox, scores);
  hipLaunchKernelGGL(select_order_decode, dim3(B_), dim3(1024), 0, stream,
                     scores, tbox, s2, b2);
  hipLaunchKernelGGL(mask_kernel, dim3(B_ * 63), dim3(256), 0, stream, b2, sup);
  hipLaunchKernelGGL(nms_out, dim3(B_), dim3(64), 0, stream, sup, b2, s2, out);
}